// Round 6
// baseline (174.583 us; speedup 1.0000x reference)
//
#include <hip/hip_runtime.h>

#define B_ 2
#define L_ 2048
#define H_ 1024
#define NH_ 16
#define HD_ 64

using short8 = __attribute__((__ext_vector_type__(8))) short;
using f32x4 = __attribute__((__ext_vector_type__(4))) float;
using f32x16 = __attribute__((__ext_vector_type__(16))) float;
typedef unsigned short u16;
typedef unsigned int u32;

__device__ __forceinline__ u16 f2bf(float f) {
  union { float f; unsigned u; } x{f};
  unsigned u = x.u;
  u = u + 0x7FFFu + ((u >> 16) & 1u);  // round-to-nearest-even
  return (u16)(u >> 16);
}

__device__ __forceinline__ float bf2f(u16 v) {
  union { u32 u; float f; } x;
  x.u = ((u32)v) << 16;
  return x.f;
}

__device__ __forceinline__ void gld16(const void* g, void* l) {
  __builtin_amdgcn_global_load_lds(
      (const __attribute__((address_space(1))) void*)g,
      (__attribute__((address_space(3))) void*)l, 16, 0, 0);
}

#define MFMA16(a, b, c) __builtin_amdgcn_mfma_f32_16x16x32_bf16((a), (b), (c), 0, 0, 0)
#define MFMA32(a, b, c) __builtin_amdgcn_mfma_f32_32x32x16_bf16((a), (b), (c), 0, 0, 0)

// ---------------- fused cast: hs|Wq|Wk|Wv|Wo -> bf16 (contiguous dst), delta prescale ----------------
__global__ void cast_all(const float* __restrict__ hs, const float* __restrict__ Wq,
                         const float* __restrict__ Wk, const float* __restrict__ Wv,
                         const float* __restrict__ Wo, const float* __restrict__ delta,
                         u16* __restrict__ dst, float* __restrict__ dsc) {
  const int t = blockIdx.x * 256 + threadIdx.x;
  const int i = t * 4;
  const float* src;
  int off;
  if (i < 4194304) {
    src = hs; off = i;
  } else {
    const int j = i - 4194304;
    const int w = j >> 20;
    off = j & 1048575;
    src = (w == 0) ? Wq : (w == 1) ? Wk : (w == 2) ? Wv : Wo;
  }
  float4 v = *(const float4*)(src + off);
  *(ushort4*)(dst + i) = make_ushort4(f2bf(v.x), f2bf(v.y), f2bf(v.z), f2bf(v.w));
  if (t < 4096) dsc[t] = delta[t] * 0.18033688011112042f;  // 0.125*log2(e)
}

// ---------------- fused QKV GEMM: [4096,1024] x [3072,1024]^T ----------------
// q (pre-scaled by tau*0.125*log2e), k written [b,h,l,d]; v written transposed [b,h,d,l]
__global__ __launch_bounds__(256) void gemm_qkv(
    const u16* __restrict__ A, const u16* __restrict__ W,
    const float* __restrict__ bq, const float* __restrict__ bk, const float* __restrict__ bv,
    const float* __restrict__ tau,
    u16* __restrict__ qg, u16* __restrict__ kg, u16* __restrict__ vTg) {
  __shared__ u16 As[128 * 64];
  __shared__ u16 Bs[128 * 64];
  const int tid = threadIdx.x;
  const int lane = tid & 63;
  const int wave = tid >> 6;
  const int wrow = (wave >> 1) * 64;
  const int wcol = (wave & 1) * 64;
  const int m0 = blockIdx.y * 128;
  const int n0 = blockIdx.x * 128;
  const int rr = tid >> 3;
  const int c8 = (tid & 7) * 8;
  f32x4 acc[4][4] = {};
  for (int kt = 0; kt < 1024; kt += 64) {
#pragma unroll
    for (int i = 0; i < 4; i++) {
      gld16(A + (size_t)(m0 + i * 32 + rr) * 1024 + kt + c8, (char*)As + i * 4096 + wave * 1024);
      gld16(W + (size_t)(n0 + i * 32 + rr) * 1024 + kt + c8, (char*)Bs + i * 4096 + wave * 1024);
    }
    __syncthreads();
#pragma unroll
    for (int kc = 0; kc < 2; kc++) {
      const int ko = kc * 32 + (lane >> 4) * 8;
      short8 af[4], bf[4];
#pragma unroll
      for (int mi = 0; mi < 4; mi++)
        af[mi] = *(const short8*)&As[(wrow + mi * 16 + (lane & 15)) * 64 + ko];
#pragma unroll
      for (int ni = 0; ni < 4; ni++)
        bf[ni] = *(const short8*)&Bs[(wcol + ni * 16 + (lane & 15)) * 64 + ko];
#pragma unroll
      for (int mi = 0; mi < 4; mi++)
#pragma unroll
        for (int ni = 0; ni < 4; ni++)
          acc[mi][ni] = MFMA16(af[mi], bf[ni], acc[mi][ni]);
    }
    __syncthreads();
  }
  const int which = n0 >> 10;  // 0=q 1=k 2=v, uniform per block
  const int b_blk = m0 >> 11;
  const float scl = (which == 0) ? tau[b_blk] * 0.18033688011112042f : 1.0f;
  const float* bias = which == 0 ? bq : (which == 1 ? bk : bv);
#pragma unroll
  for (int ni = 0; ni < 4; ni++) {
    const int n = n0 + wcol + ni * 16 + (lane & 15);
    const int nn = n & 1023;
    const int h = nn >> 6, d = nn & 63;
    const float bb = bias[nn];
#pragma unroll
    for (int mi = 0; mi < 4; mi++) {
      const int mb = m0 + wrow + mi * 16 + ((lane >> 4) << 2);
      const int b = mb >> 11;
      const int lq = mb & 2047;
      if (which == 2) {
        ushort4 pk = make_ushort4(f2bf(acc[mi][ni][0] + bb), f2bf(acc[mi][ni][1] + bb),
                                  f2bf(acc[mi][ni][2] + bb), f2bf(acc[mi][ni][3] + bb));
        *(ushort4*)&vTg[((size_t)(b * NH_ + h) * HD_ + d) * L_ + lq] = pk;
      } else {
        u16* dst = which == 0 ? qg : kg;
#pragma unroll
        for (int r = 0; r < 4; r++)
          dst[((size_t)(b * NH_ + h) * L_ + lq + r) * HD_ + d] = f2bf((acc[mi][ni][r] + bb) * scl);
      }
    }
  }
}

// ---------------- flash attention, swapped-QK^T 32x32x16, cross-block key split ----------------
// grid (16,32,2) XCD-swizzled; 256 threads; wave owns 32 q-rows x 1024 keys (kz half).
// Writes UNNORMALIZED partial ctx (bf16 [128q][64d]) + per-row (m,l) f32; merged by attn_merge.
__global__ __launch_bounds__(256) void attn(
    const u16* __restrict__ qg, const u16* __restrict__ kg, const u16* __restrict__ vTg,
    const float* __restrict__ dsc, u16* __restrict__ ctxp, float* __restrict__ mlp) {
  // per buffer: 8 K blocks (2 ktile x 4 ks) + 8 V blocks (2 kt x 2 dt x 2 ks2), 1KB each
  __shared__ u16 lds[2][8192];
  const int tid = threadIdx.x;
  const int lane = tid & 63;
  const int wv = tid >> 6;
  const int lane31 = lane & 31;
  const int hi = lane >> 5;
  // bijective XCD-chunk swizzle: nwg=1024 -> 128 consecutive wgids per XCD (kz-major)
  const int orig = blockIdx.z * 512 + blockIdx.y * 16 + blockIdx.x;
  const int wgid = (orig & 7) * 128 + (orig >> 3);
  const int kz = wgid >> 9;
  const int bh = (wgid >> 4) & 31;
  const int qblk = wgid & 15;
  const int slot = kz * 512 + bh * 16 + qblk;
  const int b = bh >> 4;
  const int q0 = qblk * 128 + wv * 32;
  const int kbase = kz * 1024;
  const u16* qb = qg + (size_t)bh * L_ * HD_;
  const u16* kb = kg + (size_t)bh * L_ * HD_;
  const u16* vb = vTg + (size_t)bh * HD_ * L_;
  const float* db = dsc + (size_t)b * L_;

  // Q fragments (B-operand): lane holds Q[q0+lane31][ks*16 + hi*8 .. +7]
  short8 qf[4];
#pragma unroll
  for (int ks = 0; ks < 4; ks++)
    qf[ks] = *(const short8*)&qb[(size_t)(q0 + lane31) * 64 + ks * 16 + hi * 8];

  // ones A-fragment: row d=0 all-ones -> l accumulates in acc_l row 0 (hi=0,r=0 lanes)
  union { u32 u[4]; short8 s; } onesu;
  const u32 ow = (lane31 == 0) ? 0x3F803F80u : 0u;
  onesu.u[0] = ow; onesu.u[1] = ow; onesu.u[2] = ow; onesu.u[3] = ow;
  const short8 onesf = onesu.s;

  f32x16 acc[2] = {};   // ctx^T: [dtile] rows d=crow(r,hi), col q=lane31
  f32x16 accl = {};     // row 0 = running softmax denominator per q
  float mrun = -__builtin_inff();

  const int i0 = 2 * wv, i1 = 2 * wv + 1;  // this wave's staging blocks

#define STAGE(bufi, j0)                                                                   \
  {                                                                                       \
    u16* bp = lds[bufi];                                                                  \
    {                                                                                     \
      const int kt = i0 >> 2, ks = i0 & 3;                                                \
      gld16(kb + (size_t)((j0) + kt * 32 + lane31) * 64 + ks * 16 + hi * 8,               \
            bp + i0 * 512 + lane * 8);                                                    \
    }                                                                                     \
    {                                                                                     \
      const int kt = i1 >> 2, ks = i1 & 3;                                                \
      gld16(kb + (size_t)((j0) + kt * 32 + lane31) * 64 + ks * 16 + hi * 8,               \
            bp + i1 * 512 + lane * 8);                                                    \
    }                                                                                     \
    {                                                                                     \
      const int kt = i0 >> 2, dt = (i0 >> 1) & 1, ks2 = i0 & 1;                           \
      gld16(vb + (size_t)(dt * 32 + lane31) * L_ + (j0) + kt * 32 + ks2 * 16 + hi * 8,    \
            bp + (8 + i0) * 512 + lane * 8);                                              \
    }                                                                                     \
    {                                                                                     \
      const int kt = i1 >> 2, dt = (i1 >> 1) & 1, ks2 = i1 & 1;                           \
      gld16(vb + (size_t)(dt * 32 + lane31) * L_ + (j0) + kt * 32 + ks2 * 16 + hi * 8,    \
            bp + (8 + i1) * 512 + lane * 8);                                              \
    }                                                                                     \
  }

  STAGE(0, kbase);
  __syncthreads();
  int cur = 0;
  for (int jt = 0; jt < 16; jt++) {
    const int j0 = kbase + jt * 64;
    if (jt + 1 < 16) STAGE(cur ^ 1, j0 + 64);
    const u16* bp = lds[cur];
#pragma unroll
    for (int kt = 0; kt < 2; kt++) {
      // S^T = K . Q^T : lane holds col q=lane31, rows key=crow(r,hi)
      f32x16 s = {};
      __builtin_amdgcn_s_setprio(1);
#pragma unroll
      for (int ks = 0; ks < 4; ks++) {
        short8 kf = *(const short8*)&bp[(kt * 4 + ks) * 512 + lane * 8];
        s = MFMA32(kf, qf[ks], s);
      }
      __builtin_amdgcn_s_setprio(0);
      // add pre-scaled delta (log2 units)
      float sv[16];
#pragma unroll
      for (int g = 0; g < 4; g++) {
        float4 dl = *(const float4*)&db[j0 + kt * 32 + g * 8 + hi * 4];
        sv[g * 4 + 0] = s[g * 4 + 0] + dl.x;
        sv[g * 4 + 1] = s[g * 4 + 1] + dl.y;
        sv[g * 4 + 2] = s[g * 4 + 2] + dl.z;
        sv[g * 4 + 3] = s[g * 4 + 3] + dl.w;
      }
      // row max (15 local + 1 cross-half shuffle)
      float t0 = fmaxf(fmaxf(sv[0], sv[1]), fmaxf(sv[2], sv[3]));
      float t1 = fmaxf(fmaxf(sv[4], sv[5]), fmaxf(sv[6], sv[7]));
      float t2 = fmaxf(fmaxf(sv[8], sv[9]), fmaxf(sv[10], sv[11]));
      float t3 = fmaxf(fmaxf(sv[12], sv[13]), fmaxf(sv[14], sv[15]));
      float pmax = fmaxf(fmaxf(t0, t1), fmaxf(t2, t3));
      pmax = fmaxf(pmax, __shfl_xor(pmax, 32));
      // defer-max (THR = 8 * log2e ~ 11.54)
      if (!__all(pmax - mrun <= 11.5f)) {
        float mnew = fmaxf(mrun, pmax);
        float al = __builtin_amdgcn_exp2f(mrun - mnew);
        mrun = mnew;
        accl[0] *= al;
#pragma unroll
        for (int dt = 0; dt < 2; dt++)
#pragma unroll
          for (int r = 0; r < 16; r++) acc[dt][r] *= al;
      }
      float p[16];
#pragma unroll
      for (int r = 0; r < 16; r++) p[r] = __builtin_amdgcn_exp2f(sv[r] - mrun);
      // T12: pack to bf16 pairs, permlane32_swap to build PV B-fragments in-register
      u32 pk[8];
#pragma unroll
      for (int i = 0; i < 8; i++)
        asm("v_cvt_pk_bf16_f32 %0, %1, %2" : "=v"(pk[i]) : "v"(p[2 * i]), "v"(p[2 * i + 1]));
      asm volatile("v_permlane32_swap_b32 %0, %1" : "+v"(pk[0]), "+v"(pk[2]));
      asm volatile("v_permlane32_swap_b32 %0, %1" : "+v"(pk[1]), "+v"(pk[3]));
      asm volatile("v_permlane32_swap_b32 %0, %1" : "+v"(pk[4]), "+v"(pk[6]));
      asm volatile("v_permlane32_swap_b32 %0, %1" : "+v"(pk[5]), "+v"(pk[7]));
      union U8 { u32 u[4]; short8 s; } f0, f1;
      f0.u[0] = pk[0]; f0.u[1] = pk[1]; f0.u[2] = pk[2]; f0.u[3] = pk[3];
      f1.u[0] = pk[4]; f1.u[1] = pk[5]; f1.u[2] = pk[6]; f1.u[3] = pk[7];
      // ctx^T += V^T . P ; accl += ones_row0 . P (softmax denominator via MFMA)
      __builtin_amdgcn_s_setprio(1);
#pragma unroll
      for (int ks2 = 0; ks2 < 2; ks2++) {
        short8 pf = ks2 ? f1.s : f0.s;
#pragma unroll
        for (int dt = 0; dt < 2; dt++) {
          short8 vf = *(const short8*)&bp[(8 + kt * 4 + dt * 2 + ks2) * 512 + lane * 8];
          acc[dt] = MFMA32(vf, pf, acc[dt]);
        }
        accl = MFMA32(onesf, pf, accl);
      }
      __builtin_amdgcn_s_setprio(0);
    }
    __syncthreads();
    cur ^= 1;
  }

  // epilogue: write (m,l) per q-row; transpose ctx^T -> [q][d] via swizzled LDS; store partial
  __syncthreads();
  if (hi == 0) {
    float2 v2;
    v2.x = mrun;
    v2.y = accl[0];
    *(float2*)&mlp[((size_t)slot * 128 + wv * 32 + lane31) * 2] = v2;
  }
  u16* tw = lds[0] + wv * 2048;  // 4KB per wave: [32 q][64 d] bf16, XOR-swizzled
#pragma unroll
  for (int dt = 0; dt < 2; dt++)
#pragma unroll
    for (int g = 0; g < 4; g++) {
      ushort4 w4 = make_ushort4(f2bf(acc[dt][g * 4 + 0]), f2bf(acc[dt][g * 4 + 1]),
                                f2bf(acc[dt][g * 4 + 2]), f2bf(acc[dt][g * 4 + 3]));
      const int d0 = dt * 32 + g * 8 + hi * 4;
      const int byte = (lane31 * 128 + d0 * 2) ^ ((lane31 & 15) << 3);
      *(ushort4*)((char*)tw + byte) = w4;
    }
  asm volatile("s_waitcnt lgkmcnt(0)" ::: "memory");
  u16* pbase = ctxp + (size_t)slot * 8192 + wv * 32 * 64;
#pragma unroll
  for (int i = 0; i < 16; i++) {
    const int qr = 2 * i + hi;
    const int byte = (qr * 128 + lane31 * 4) ^ ((qr & 15) << 3);
    const u32 val = *(const u32*)((const char*)tw + byte);
    *(u32*)&pbase[(size_t)qr * 64 + lane31 * 2] = val;
  }
}

// ---------------- merge the two key-half partials ----------------
// grid 512 (bh*16+qblk), 256 threads; thread t: q = t>>1, d-range = (t&1)*32 .. +32
__global__ __launch_bounds__(256) void attn_merge(
    const u16* __restrict__ ctxp, const float* __restrict__ mlp, u16* __restrict__ ctxg) {
  const int blk = blockIdx.x;
  const int bh = blk >> 4, qblk = blk & 15;
  const int t = threadIdx.x;
  const int q = t >> 1;
  const int d0 = (t & 1) * 32;
  const int slot0 = blk;
  const int slot1 = 512 + blk;
  const float2 ml0 = *(const float2*)&mlp[((size_t)slot0 * 128 + q) * 2];
  const float2 ml1 = *(const float2*)&mlp[((size_t)slot1 * 128 + q) * 2];
  const float M = fmaxf(ml0.x, ml1.x);
  const float a0 = __builtin_amdgcn_exp2f(ml0.x - M);
  const float a1 = __builtin_amdgcn_exp2f(ml1.x - M);
  const float inv = 1.0f / (ml0.y * a0 + ml1.y * a1);
  const float s0 = a0 * inv, s1 = a1 * inv;
  const int b = bh >> 4, h = bh & 15;
  const u16* p0 = ctxp + (size_t)slot0 * 8192 + q * 64 + d0;
  const u16* p1 = ctxp + (size_t)slot1 * 8192 + q * 64 + d0;
  u16* po = ctxg + ((size_t)b * L_ + qblk * 128 + q) * 1024 + h * 64 + d0;
#pragma unroll
  for (int i = 0; i < 4; i++) {
    short8 u0 = *(const short8*)(p0 + i * 8);
    short8 u1 = *(const short8*)(p1 + i * 8);
    ushort4 o[2];
#pragma unroll
    for (int j = 0; j < 8; j++) {
      float f = bf2f((u16)u0[j]) * s0 + bf2f((u16)u1[j]) * s1;
      ((u16*)o)[j] = f2bf(f);
    }
    *(ushort4*)(po + i * 8 + 0) = o[0];
    *(ushort4*)(po + i * 8 + 4) = o[1];
  }
}

// ---------------- output GEMM: ctx[4096,1024] x Wo[1024,1024]^T + bo -> f32 ----------------
__global__ __launch_bounds__(256) void gemm_out(
    const u16* __restrict__ A, const u16* __restrict__ W,
    const float* __restrict__ bo, float* __restrict__ out) {
  __shared__ u16 As[128 * 64];
  __shared__ u16 Bs[128 * 64];
  const int tid = threadIdx.x;
  const int lane = tid & 63;
  const int wave = tid >> 6;
  const int wrow = (wave >> 1) * 64;
  const int wcol = (wave & 1) * 64;
  const int m0 = blockIdx.y * 128;
  const int n0 = blockIdx.x * 128;
  const int rr = tid >> 3;
  const int c8 = (tid & 7) * 8;
  f32x4 acc[4][4] = {};
  for (int kt = 0; kt < 1024; kt += 64) {
#pragma unroll
    for (int i = 0; i < 4; i++) {
      gld16(A + (size_t)(m0 + i * 32 + rr) * 1024 + kt + c8, (char*)As + i * 4096 + wave * 1024);
      gld16(W + (size_t)(n0 + i * 32 + rr) * 1024 + kt + c8, (char*)Bs + i * 4096 + wave * 1024);
    }
    __syncthreads();
#pragma unroll
    for (int kc = 0; kc < 2; kc++) {
      const int ko = kc * 32 + (lane >> 4) * 8;
      short8 af[4], bf[4];
#pragma unroll
      for (int mi = 0; mi < 4; mi++)
        af[mi] = *(const short8*)&As[(wrow + mi * 16 + (lane & 15)) * 64 + ko];
#pragma unroll
      for (int ni = 0; ni < 4; ni++)
        bf[ni] = *(const short8*)&Bs[(wcol + ni * 16 + (lane & 15)) * 64 + ko];
#pragma unroll
      for (int mi = 0; mi < 4; mi++)
#pragma unroll
        for (int ni = 0; ni < 4; ni++)
          acc[mi][ni] = MFMA16(af[mi], bf[ni], acc[mi][ni]);
    }
    __syncthreads();
  }
#pragma unroll
  for (int ni = 0; ni < 4; ni++) {
    const int n = n0 + wcol + ni * 16 + (lane & 15);
    const float bb = bo[n];
#pragma unroll
    for (int mi = 0; mi < 4; mi++) {
      const int mb = m0 + wrow + mi * 16 + ((lane >> 4) << 2);
#pragma unroll
      for (int r = 0; r < 4; r++)
        out[(size_t)(mb + r) * 1024 + n] = acc[mi][ni][r] + bb;
    }
  }
}

extern "C" void kernel_launch(void* const* d_in, const int* in_sizes, int n_in,
                              void* d_out, int out_size, void* d_ws, size_t ws_size,
                              hipStream_t stream) {
  const float* hs = (const float*)d_in[0];
  const float* tau = (const float*)d_in[1];
  const float* delta = (const float*)d_in[2];
  const float* Wq = (const float*)d_in[3];
  const float* bq = (const float*)d_in[4];
  const float* Wk = (const float*)d_in[5];
  const float* bk = (const float*)d_in[6];
  const float* Wv = (const float*)d_in[7];
  const float* bv = (const float*)d_in[8];
  const float* Wo = (const float*)d_in[9];
  const float* bo = (const float*)d_in[10];
  float* out = (float*)d_out;

  u16* ws = (u16*)d_ws;
  u16* hsb  = ws;                   // 4194304
  u16* wqkv = ws + 4194304;         // 3145728 (Wq|Wk|Wv)
  u16* wob  = ws + 7340032;         // 1048576
  u16* qg   = ws + 8388608;         // 4194304
  u16* kg   = ws + 12582912;        // 4194304
  u16* vTg  = ws + 16777216;        // 4194304
  u16* ctxg = ws + 20971520;        // 4194304
  float* dsc = (float*)(ws + 25165824);   // 4096 f32 (8192 u16)
  u16* ctxp = ws + 25174016;              // 1024*8192 u16 = 16MB
  float* mlp = (float*)(ws + 33562624);   // 1024*128*2 f32 (524288 u16)

  cast_all<<<8192, 256, 0, stream>>>(hs, Wq, Wk, Wv, Wo, delta, ws, dsc);

  gemm_qkv<<<dim3(24, 32), 256, 0, stream>>>(hsb, wqkv, bq, bk, bv, tau, qg, kg, vTg);
  attn<<<dim3(16, 32, 2), 256, 0, stream>>>(qg, kg, vTg, dsc, ctxp, mlp);
  attn_merge<<<512, 256, 0, stream>>>(ctxp, mlp, ctxg);
  gemm_out<<<dim3(8, 32), 256, 0, stream>>>(ctxg, wob, bo, out);
}

// Round 7
// 151.361 us; speedup vs baseline: 1.1534x; 1.1534x over previous
//
#include <hip/hip_runtime.h>

#define B_ 2
#define L_ 2048
#define H_ 1024
#define NH_ 16
#define HD_ 64

using short8 = __attribute__((__ext_vector_type__(8))) short;
using f32x4 = __attribute__((__ext_vector_type__(4))) float;
using f32x16 = __attribute__((__ext_vector_type__(16))) float;
typedef unsigned short u16;
typedef unsigned int u32;

__device__ __forceinline__ u16 f2bf(float f) {
  union { float f; unsigned u; } x{f};
  unsigned u = x.u;
  u = u + 0x7FFFu + ((u >> 16) & 1u);  // round-to-nearest-even
  return (u16)(u >> 16);
}

__device__ __forceinline__ void gld16(const void* g, void* l) {
  __builtin_amdgcn_global_load_lds(
      (const __attribute__((address_space(1))) void*)g,
      (__attribute__((address_space(3))) void*)l, 16, 0, 0);
}

#define MFMA16(a, b, c) __builtin_amdgcn_mfma_f32_16x16x32_bf16((a), (b), (c), 0, 0, 0)
#define MFMA32(a, b, c) __builtin_amdgcn_mfma_f32_32x32x16_bf16((a), (b), (c), 0, 0, 0)

// ---------------- fused cast: hs|Wq|Wk|Wv|Wo -> bf16 (contiguous dst), delta prescale ----------------
__global__ void cast_all(const float* __restrict__ hs, const float* __restrict__ Wq,
                         const float* __restrict__ Wk, const float* __restrict__ Wv,
                         const float* __restrict__ Wo, const float* __restrict__ delta,
                         u16* __restrict__ dst, float* __restrict__ dsc) {
  const int t = blockIdx.x * 256 + threadIdx.x;
  const int i = t * 4;
  const float* src;
  int off;
  if (i < 4194304) {
    src = hs; off = i;
  } else {
    const int j = i - 4194304;
    const int w = j >> 20;
    off = j & 1048575;
    src = (w == 0) ? Wq : (w == 1) ? Wk : (w == 2) ? Wv : Wo;
  }
  float4 v = *(const float4*)(src + off);
  *(ushort4*)(dst + i) = make_ushort4(f2bf(v.x), f2bf(v.y), f2bf(v.z), f2bf(v.w));
  if (t < 4096) dsc[t] = delta[t] * 0.18033688011112042f;  // 0.125*log2(e)
}

// ---------------- QKV GEMM, 256x256 tile, counted-vmcnt pipeline ----------------
// C[m][n] = sum_k A[m][k] * W[n][k]; M=4096, N=3072, K=1024. 512 thr (8 waves, 2x4).
// LDS 128KB: As/Bs double-buffered [256 rows][64 k], 16B granules XOR-swizzled by row&7.
// Schedule per K-step t: issue stage(t+1) -> s_waitcnt vmcnt(8) (stage(t) done,
// stage(t+1) stays in flight) -> s_barrier -> 4 quadrant phases (16 MFMA each).
__global__ __launch_bounds__(512) void gemm_qkv256(
    const u16* __restrict__ A, const u16* __restrict__ W,
    const float* __restrict__ bq, const float* __restrict__ bk, const float* __restrict__ bv,
    const float* __restrict__ tau,
    u16* __restrict__ qg, u16* __restrict__ kg, u16* __restrict__ vTg) {
  __shared__ u16 As[2][256 * 64];
  __shared__ u16 Bs[2][256 * 64];
  const int tid = threadIdx.x;
  const int lane = tid & 63;
  const int wid = tid >> 6;
  const int wr = wid >> 2;   // 0..1 -> rows wr*128..+128
  const int wc = wid & 3;    // 0..3 -> cols wc*64..+64
  // bijective XCD swizzle: 192 blocks -> 24 consecutive per XCD (W-panel locality)
  const int orig = blockIdx.y * 12 + blockIdx.x;
  const int wg = (orig & 7) * 24 + (orig >> 3);
  const int m0 = (wg & 15) * 256;
  const int n0 = (wg >> 4) * 256;

  const int srow = tid >> 3;          // 0..63 within each li group
  const int sg = tid & 7;             // dest granule

#define STAGE256(slot, t_)                                                              \
  {                                                                                     \
    const int kt64 = (t_) * 64;                                                         \
    _Pragma("unroll") for (int li = 0; li < 4; li++) {                                  \
      const int row = li * 64 + srow;                                                   \
      const int gsrc = sg ^ (row & 7);                                                  \
      gld16(A + (size_t)(m0 + row) * 1024 + kt64 + gsrc * 8,                            \
            (char*)As[slot] + li * 8192 + wid * 1024 + lane * 16);                      \
      gld16(W + (size_t)(n0 + row) * 1024 + kt64 + gsrc * 8,                            \
            (char*)Bs[slot] + li * 8192 + wid * 1024 + lane * 16);                      \
    }                                                                                   \
  }

  f32x4 acc[8][4] = {};

  STAGE256(0, 0);
  STAGE256(1, 1);

  for (int t = 0; t < 16; t++) {
    if (t >= 1 && t + 1 < 16) STAGE256((t + 1) & 1, t + 1);
    if (t + 1 < 16) {
      asm volatile("s_waitcnt vmcnt(8)" ::: "memory");
    } else {
      asm volatile("s_waitcnt vmcnt(0)" ::: "memory");
    }
    asm volatile("s_barrier" ::: "memory");
    const u16* Ab = As[t & 1];
    const u16* Bb = Bs[t & 1];
    short8 bf[4];
#pragma unroll
    for (int q = 0; q < 4; q++) {
      const int mh = q & 1, ks = q >> 1;
      const int g0 = ks * 4 + (lane >> 4);
      if (mh == 0) {
#pragma unroll
        for (int ni = 0; ni < 4; ni++) {
          const int r = wc * 64 + ni * 16 + (lane & 15);
          bf[ni] = *(const short8*)((const char*)Bb + r * 128 + ((g0 ^ (r & 7)) << 4));
        }
      }
      short8 af[4];
#pragma unroll
      for (int mi = 0; mi < 4; mi++) {
        const int r = wr * 128 + (mh * 4 + mi) * 16 + (lane & 15);
        af[mi] = *(const short8*)((const char*)Ab + r * 128 + ((g0 ^ (r & 7)) << 4));
      }
      __builtin_amdgcn_s_setprio(1);
#pragma unroll
      for (int mi = 0; mi < 4; mi++)
#pragma unroll
        for (int ni = 0; ni < 4; ni++)
          acc[mh * 4 + mi][ni] = MFMA16(af[mi], bf[ni], acc[mh * 4 + mi][ni]);
      __builtin_amdgcn_s_setprio(0);
      asm volatile("s_barrier" ::: "memory");
    }
  }

  const int which = n0 >> 10;  // 0=q 1=k 2=v, uniform per block (1024/256=4 blocks each)
  const int b_blk = m0 >> 11;
  const float scl = (which == 0) ? tau[b_blk] * 0.18033688011112042f : 1.0f;
  const float* bias = which == 0 ? bq : (which == 1 ? bk : bv);
#pragma unroll
  for (int ni = 0; ni < 4; ni++) {
    const int n = n0 + wc * 64 + ni * 16 + (lane & 15);
    const int nn = n & 1023;
    const int h = nn >> 6, d = nn & 63;
    const float bb = bias[nn];
#pragma unroll
    for (int mi = 0; mi < 8; mi++) {
      const int mb = m0 + wr * 128 + mi * 16 + ((lane >> 4) << 2);
      const int b = mb >> 11;
      const int lq = mb & 2047;
      if (which == 2) {
        ushort4 pk = make_ushort4(f2bf(acc[mi][ni][0] + bb), f2bf(acc[mi][ni][1] + bb),
                                  f2bf(acc[mi][ni][2] + bb), f2bf(acc[mi][ni][3] + bb));
        *(ushort4*)&vTg[((size_t)(b * NH_ + h) * HD_ + d) * L_ + lq] = pk;
      } else {
        u16* dst = which == 0 ? qg : kg;
#pragma unroll
        for (int r = 0; r < 4; r++)
          dst[((size_t)(b * NH_ + h) * L_ + lq + r) * HD_ + d] = f2bf((acc[mi][ni][r] + bb) * scl);
      }
    }
  }
}

// ---------------- flash attention, swapped-QK^T 32x32x16 (R5 structure) ----------------
// grid (16,32) XCD-swizzled; 256 threads; each wave owns 32 q-rows x all keys, KVBLK=64 dbuf.
__global__ __launch_bounds__(256) void attn(
    const u16* __restrict__ qg, const u16* __restrict__ kg, const u16* __restrict__ vTg,
    const float* __restrict__ dsc, u16* __restrict__ ctxg) {
  // per buffer: 8 K blocks (2 ktile x 4 ks) + 8 V blocks (2 kt x 2 dt x 2 ks2), 1KB each
  __shared__ u16 lds[2][8192];
  const int tid = threadIdx.x;
  const int lane = tid & 63;
  const int wv = tid >> 6;
  const int lane31 = lane & 31;
  const int hi = lane >> 5;
  // bijective XCD-chunk swizzle: nwg=512 -> 64 consecutive wgids (4 bh) per XCD
  const int orig = blockIdx.y * 16 + blockIdx.x;
  const int wgid = (orig & 7) * 64 + (orig >> 3);
  const int bh = wgid >> 4;
  const int qblk = wgid & 15;
  const int b = bh >> 4;
  const int h = bh & 15;
  const int q0 = qblk * 128 + wv * 32;
  const u16* qb = qg + (size_t)bh * L_ * HD_;
  const u16* kb = kg + (size_t)bh * L_ * HD_;
  const u16* vb = vTg + (size_t)bh * HD_ * L_;
  const float* db = dsc + (size_t)b * L_;

  // Q fragments (B-operand): lane holds Q[q0+lane31][ks*16 + hi*8 .. +7]
  short8 qf[4];
#pragma unroll
  for (int ks = 0; ks < 4; ks++)
    qf[ks] = *(const short8*)&qb[(size_t)(q0 + lane31) * 64 + ks * 16 + hi * 8];

  // ones A-fragment: row d=0 all-ones -> l accumulates in acc_l row 0 (hi=0,r=0 lanes)
  union { u32 u[4]; short8 s; } onesu;
  const u32 ow = (lane31 == 0) ? 0x3F803F80u : 0u;
  onesu.u[0] = ow; onesu.u[1] = ow; onesu.u[2] = ow; onesu.u[3] = ow;
  const short8 onesf = onesu.s;

  f32x16 acc[2] = {};   // ctx^T: [dtile] rows d=crow(r,hi), col q=lane31
  f32x16 accl = {};     // row 0 = running softmax denominator per q
  float mrun = -__builtin_inff();

  const int i0 = 2 * wv, i1 = 2 * wv + 1;  // this wave's staging blocks

#define STAGE(bufi, j0)                                                                   \
  {                                                                                       \
    u16* bp = lds[bufi];                                                                  \
    {                                                                                     \
      const int kt = i0 >> 2, ks = i0 & 3;                                                \
      gld16(kb + (size_t)((j0) + kt * 32 + lane31) * 64 + ks * 16 + hi * 8,               \
            bp + i0 * 512 + lane * 8);                                                    \
    }                                                                                     \
    {                                                                                     \
      const int kt = i1 >> 2, ks = i1 & 3;                                                \
      gld16(kb + (size_t)((j0) + kt * 32 + lane31) * 64 + ks * 16 + hi * 8,               \
            bp + i1 * 512 + lane * 8);                                                    \
    }                                                                                     \
    {                                                                                     \
      const int kt = i0 >> 2, dt = (i0 >> 1) & 1, ks2 = i0 & 1;                           \
      gld16(vb + (size_t)(dt * 32 + lane31) * L_ + (j0) + kt * 32 + ks2 * 16 + hi * 8,    \
            bp + (8 + i0) * 512 + lane * 8);                                              \
    }                                                                                     \
    {                                                                                     \
      const int kt = i1 >> 2, dt = (i1 >> 1) & 1, ks2 = i1 & 1;                           \
      gld16(vb + (size_t)(dt * 32 + lane31) * L_ + (j0) + kt * 32 + ks2 * 16 + hi * 8,    \
            bp + (8 + i1) * 512 + lane * 8);                                              \
    }                                                                                     \
  }

  STAGE(0, 0);
  __syncthreads();
  int cur = 0;
  for (int jt = 0; jt < L_ / 64; jt++) {
    const int j0 = jt * 64;
    if (jt + 1 < L_ / 64) STAGE(cur ^ 1, j0 + 64);
    const u16* bp = lds[cur];
#pragma unroll
    for (int kt = 0; kt < 2; kt++) {
      // S^T = K . Q^T : lane holds col q=lane31, rows key=crow(r,hi)
      f32x16 s = {};
      __builtin_amdgcn_s_setprio(1);
#pragma unroll
      for (int ks = 0; ks < 4; ks++) {
        short8 kf = *(const short8*)&bp[(kt * 4 + ks) * 512 + lane * 8];
        s = MFMA32(kf, qf[ks], s);
      }
      __builtin_amdgcn_s_setprio(0);
      // add pre-scaled delta (log2 units)
      float sv[16];
#pragma unroll
      for (int g = 0; g < 4; g++) {
        float4 dl = *(const float4*)&db[j0 + kt * 32 + g * 8 + hi * 4];
        sv[g * 4 + 0] = s[g * 4 + 0] + dl.x;
        sv[g * 4 + 1] = s[g * 4 + 1] + dl.y;
        sv[g * 4 + 2] = s[g * 4 + 2] + dl.z;
        sv[g * 4 + 3] = s[g * 4 + 3] + dl.w;
      }
      // row max (15 local + 1 cross-half shuffle)
      float t0 = fmaxf(fmaxf(sv[0], sv[1]), fmaxf(sv[2], sv[3]));
      float t1 = fmaxf(fmaxf(sv[4], sv[5]), fmaxf(sv[6], sv[7]));
      float t2 = fmaxf(fmaxf(sv[8], sv[9]), fmaxf(sv[10], sv[11]));
      float t3 = fmaxf(fmaxf(sv[12], sv[13]), fmaxf(sv[14], sv[15]));
      float pmax = fmaxf(fmaxf(t0, t1), fmaxf(t2, t3));
      pmax = fmaxf(pmax, __shfl_xor(pmax, 32));
      // defer-max (THR = 8 * log2e ~ 11.54)
      if (!__all(pmax - mrun <= 11.5f)) {
        float mnew = fmaxf(mrun, pmax);
        float al = __builtin_amdgcn_exp2f(mrun - mnew);
        mrun = mnew;
        accl[0] *= al;
#pragma unroll
        for (int dt = 0; dt < 2; dt++)
#pragma unroll
          for (int r = 0; r < 16; r++) acc[dt][r] *= al;
      }
      float p[16];
#pragma unroll
      for (int r = 0; r < 16; r++) p[r] = __builtin_amdgcn_exp2f(sv[r] - mrun);
      // T12: pack to bf16 pairs, permlane32_swap to build PV B-fragments in-register
      u32 pk[8];
#pragma unroll
      for (int i = 0; i < 8; i++)
        asm("v_cvt_pk_bf16_f32 %0, %1, %2" : "=v"(pk[i]) : "v"(p[2 * i]), "v"(p[2 * i + 1]));
      asm volatile("v_permlane32_swap_b32 %0, %1" : "+v"(pk[0]), "+v"(pk[2]));
      asm volatile("v_permlane32_swap_b32 %0, %1" : "+v"(pk[1]), "+v"(pk[3]));
      asm volatile("v_permlane32_swap_b32 %0, %1" : "+v"(pk[4]), "+v"(pk[6]));
      asm volatile("v_permlane32_swap_b32 %0, %1" : "+v"(pk[5]), "+v"(pk[7]));
      union U8 { u32 u[4]; short8 s; } f0, f1;
      f0.u[0] = pk[0]; f0.u[1] = pk[1]; f0.u[2] = pk[2]; f0.u[3] = pk[3];
      f1.u[0] = pk[4]; f1.u[1] = pk[5]; f1.u[2] = pk[6]; f1.u[3] = pk[7];
      // ctx^T += V^T . P ; accl += ones_row0 . P (softmax denominator via MFMA)
      __builtin_amdgcn_s_setprio(1);
#pragma unroll
      for (int ks2 = 0; ks2 < 2; ks2++) {
        short8 pf = ks2 ? f1.s : f0.s;
#pragma unroll
        for (int dt = 0; dt < 2; dt++) {
          short8 vf = *(const short8*)&bp[(8 + kt * 4 + dt * 2 + ks2) * 512 + lane * 8];
          acc[dt] = MFMA32(vf, pf, acc[dt]);
        }
        accl = MFMA32(onesf, pf, accl);
      }
      __builtin_amdgcn_s_setprio(0);
    }
    __syncthreads();
    cur ^= 1;
  }

  // epilogue: transpose ctx^T -> ctx via swizzled per-wave LDS tile, coalesced store
  __syncthreads();
  u16* tw = lds[0] + wv * 2048;  // 4KB per wave: [32 q][64 d] bf16, XOR-swizzled
  const float l0 = accl[0];
  const float l1 = __shfl_xor(l0, 32);
  const float inv = 1.0f / (hi ? l1 : l0);
#pragma unroll
  for (int dt = 0; dt < 2; dt++)
#pragma unroll
    for (int g = 0; g < 4; g++) {
      ushort4 w4 = make_ushort4(f2bf(acc[dt][g * 4 + 0] * inv), f2bf(acc[dt][g * 4 + 1] * inv),
                                f2bf(acc[dt][g * 4 + 2] * inv), f2bf(acc[dt][g * 4 + 3] * inv));
      const int d0 = dt * 32 + g * 8 + hi * 4;
      const int byte = (lane31 * 128 + d0 * 2) ^ ((lane31 & 15) << 3);
      *(ushort4*)((char*)tw + byte) = w4;
    }
  asm volatile("s_waitcnt lgkmcnt(0)" ::: "memory");
  const size_t obase = ((size_t)b * L_ + q0) * 1024 + h * 64;
#pragma unroll
  for (int i = 0; i < 16; i++) {
    const int qr = 2 * i + hi;
    const int byte = (qr * 128 + lane31 * 4) ^ ((qr & 15) << 3);
    const u32 val = *(const u32*)((const char*)tw + byte);
    *(u32*)&ctxg[obase + (size_t)qr * 1024 + lane31 * 2] = val;
  }
}

// ---------------- output GEMM: ctx[4096,1024] x Wo[1024,1024]^T + bo -> f32 ----------------
__global__ __launch_bounds__(256) void gemm_out(
    const u16* __restrict__ A, const u16* __restrict__ W,
    const float* __restrict__ bo, float* __restrict__ out) {
  __shared__ u16 As[128 * 64];
  __shared__ u16 Bs[128 * 64];
  const int tid = threadIdx.x;
  const int lane = tid & 63;
  const int wave = tid >> 6;
  const int wrow = (wave >> 1) * 64;
  const int wcol = (wave & 1) * 64;
  const int m0 = blockIdx.y * 128;
  const int n0 = blockIdx.x * 128;
  const int rr = tid >> 3;
  const int c8 = (tid & 7) * 8;
  f32x4 acc[4][4] = {};
  for (int kt = 0; kt < 1024; kt += 64) {
#pragma unroll
    for (int i = 0; i < 4; i++) {
      gld16(A + (size_t)(m0 + i * 32 + rr) * 1024 + kt + c8, (char*)As + i * 4096 + wave * 1024);
      gld16(W + (size_t)(n0 + i * 32 + rr) * 1024 + kt + c8, (char*)Bs + i * 4096 + wave * 1024);
    }
    __syncthreads();
#pragma unroll
    for (int kc = 0; kc < 2; kc++) {
      const int ko = kc * 32 + (lane >> 4) * 8;
      short8 af[4], bf[4];
#pragma unroll
      for (int mi = 0; mi < 4; mi++)
        af[mi] = *(const short8*)&As[(wrow + mi * 16 + (lane & 15)) * 64 + ko];
#pragma unroll
      for (int ni = 0; ni < 4; ni++)
        bf[ni] = *(const short8*)&Bs[(wcol + ni * 16 + (lane & 15)) * 64 + ko];
#pragma unroll
      for (int mi = 0; mi < 4; mi++)
#pragma unroll
        for (int ni = 0; ni < 4; ni++)
          acc[mi][ni] = MFMA16(af[mi], bf[ni], acc[mi][ni]);
    }
    __syncthreads();
  }
#pragma unroll
  for (int ni = 0; ni < 4; ni++) {
    const int n = n0 + wcol + ni * 16 + (lane & 15);
    const float bb = bo[n];
#pragma unroll
    for (int mi = 0; mi < 4; mi++) {
      const int mb = m0 + wrow + mi * 16 + ((lane >> 4) << 2);
#pragma unroll
      for (int r = 0; r < 4; r++)
        out[(size_t)(mb + r) * 1024 + n] = acc[mi][ni][r] + bb;
    }
  }
}

extern "C" void kernel_launch(void* const* d_in, const int* in_sizes, int n_in,
                              void* d_out, int out_size, void* d_ws, size_t ws_size,
                              hipStream_t stream) {
  const float* hs = (const float*)d_in[0];
  const float* tau = (const float*)d_in[1];
  const float* delta = (const float*)d_in[2];
  const float* Wq = (const float*)d_in[3];
  const float* bq = (const float*)d_in[4];
  const float* Wk = (const float*)d_in[5];
  const float* bk = (const float*)d_in[6];
  const float* Wv = (const float*)d_in[7];
  const float* bv = (const float*)d_in[8];
  const float* Wo = (const float*)d_in[9];
  const float* bo = (const float*)d_in[10];
  float* out = (float*)d_out;

  u16* ws = (u16*)d_ws;
  u16* hsb  = ws;                   // 4194304
  u16* wqkv = ws + 4194304;         // 3145728 (Wq|Wk|Wv)
  u16* wob  = ws + 7340032;         // 1048576
  u16* qg   = ws + 8388608;         // 4194304
  u16* kg   = ws + 12582912;        // 4194304
  u16* vTg  = ws + 16777216;        // 4194304
  u16* ctxg = ws + 20971520;        // 4194304
  float* dsc = (float*)(ws + 25165824);  // 4096 floats

  cast_all<<<8192, 256, 0, stream>>>(hs, Wq, Wk, Wv, Wo, delta, ws, dsc);

  gemm_qkv256<<<dim3(12, 16), 512, 0, stream>>>(hsb, wqkv, bq, bk, bv, tau, qg, kg, vTg);
  attn<<<dim3(16, 32), 256, 0, stream>>>(qg, kg, vTg, dsc, ctxg);
  gemm_out<<<dim3(8, 32), 256, 0, stream>>>(ctxg, wob, bo, out);
}